// Round 1
// baseline (5842.219 us; speedup 1.0000x reference)
//
#include <hip/hip_runtime.h>
#include <math.h>

#define TPB 512

// rcp + 1 Newton-Raphson step: ~0.5 ulp, ~4 inst vs ~10 for IEEE div
__device__ __forceinline__ float rcp_nr(float x) {
    float r = __builtin_amdgcn_rcpf(x);
    return r * fmaf(-x, r, 2.0f);
}

// DPP-based add of shifted value; bound_ctrl=true -> invalid source lanes read 0
template<int CTRL>
__device__ __forceinline__ float dpp_add(float x) {
    int y = __builtin_amdgcn_update_dpp(0, __float_as_int(x), CTRL, 0xF, 0xF, true);
    return x + __int_as_float(y);
}

// Full 64-lane sum; result valid in lane 63. Pure VALU (no LDS pipe).
__device__ __forceinline__ float reduce_wave64(float x) {
    x = dpp_add<0x111>(x); // row_shr:1
    x = dpp_add<0x112>(x); // row_shr:2
    x = dpp_add<0x114>(x); // row_shr:4
    x = dpp_add<0x118>(x); // row_shr:8  -> lane15 of each row = row sum
    x = dpp_add<0x142>(x); // row_bcast15 -> lane31 = rows0+1, lane63 = rows2+3
    x = dpp_add<0x143>(x); // row_bcast31 -> lane63 = total
    return x;
}

__global__ __launch_bounds__(TPB, 2)
void sgd_filter(const float* __restrict__ sos_in,
                const float* __restrict__ target,
                float* __restrict__ out) {
    // sections padded to 8 floats: [b0 b1 b2 a0 a1 a2 pad pad] -> b128+b64 broadcast reads
    __shared__ __align__(16) float sos[16 * 8];
    __shared__ float gradp[8][96];   // per-wave partial gradients (deterministic combine)

    const int tid = threadIdx.x;
    const int wv = tid >> 6;
    const int upd_idx = (tid / 6) * 8 + (tid % 6); // only meaningful for tid<96

    if (tid < 96) sos[upd_idx] = sos_in[tid];

    // Per-thread frequency constants (fixed across iterations)
    const float w  = (float)((double)tid * (3.14159265358979323846 / 511.0));
    const float c1 = cosf(w);
    const float s1 = -sinf(w);           // z1 = e^{-jw} = (c1, s1)
    const float c2 = c1 * c1 - s1 * s1;  // z2 = z1*z1 (matches JAX exactly)
    const float s2 = 2.0f * c1 * s1;
    const float tgt = target[tid];
    const float KC = 40.0f / (512.0f * 2.302585092994046f); // 40/(n*ln10)

    __syncthreads();

    float Br_[16], Bi_[16], Ar_[16], Ai_[16], iA_[16];

    for (int it = 0; it < 1000; ++it) {
        // ---------------- forward: H = prod_s B_s/A_s ----------------
        float Hr = 1.0f, Hi = 0.0f;
#pragma unroll
        for (int s = 0; s < 16; ++s) {
            float4 v0 = *(const float4*)&sos[s * 8];     // b0 b1 b2 a0
            float2 v1 = *(const float2*)&sos[s * 8 + 4]; // a1 a2
            const float b0 = v0.x, b1 = v0.y, b2 = v0.z;
            const float a0 = v0.w, a1 = v1.x, a2 = v1.y;
            const float Br = fmaf(b2, c2, fmaf(b1, c1, b0));
            const float Bi = fmaf(b2, s2, b1 * s1);
            const float Ar = fmaf(a2, c2, fmaf(a1, c1, a0));
            const float Ai = fmaf(a2, s2, a1 * s1);
            const float inv = rcp_nr(fmaf(Ar, Ar, Ai * Ai));
            const float qr = fmaf(Br, Ar, Bi * Ai) * inv;
            const float qi = fmaf(Bi, Ar, -(Br * Ai)) * inv;
            const float nHr = fmaf(Hr, qr, -(Hi * qi));
            const float nHi = fmaf(Hr, qi, Hi * qr);
            Hr = nHr; Hi = nHi;
            Br_[s] = Br; Bi_[s] = Bi; Ar_[s] = Ar; Ai_[s] = Ai; iA_[s] = inv;
        }
        const float mag  = sqrtf(fmaf(Hr, Hr, Hi * Hi));
        const float indB = 20.0f * log10f(mag + 1e-8f);
        const float diff = indB - tgt;
        // K = KC * d * mag/(mag+eps)  (chain rule through log10, sqrt, |H|^2)
        const float K = KC * diff * mag * rcp_nr(mag + 1e-8f);

        // ---------------- backward + per-wave reduce ----------------
#pragma unroll
        for (int s = 0; s < 16; ++s) {
            const float Br = Br_[s], Bi = Bi_[s], Ar = Ar_[s], Ai = Ai_[s];
            const float iB = rcp_nr(fmaf(Br, Br, Bi * Bi));
            const float UB = K * iB;
            const float Pb = UB * Br, Qb = UB * Bi;
            const float UA = -K * iA_[s];
            const float Pa = UA * Ar, Qa = UA * Ai;

            float g0 = reduce_wave64(Pb);                        // d/db0: Re(conj B)
            float g1 = reduce_wave64(fmaf(c1, Pb, s1 * Qb));     // d/db1: Re(z1 conj B)
            float g2 = reduce_wave64(fmaf(c2, Pb, s2 * Qb));     // d/db2: Re(z2 conj B)
            float g3 = reduce_wave64(Pa);                        // d/da0
            float g4 = reduce_wave64(fmaf(c1, Pa, s1 * Qa));     // d/da1
            float g5 = reduce_wave64(fmaf(c2, Pa, s2 * Qa));     // d/da2

            if ((tid & 63) == 63) {
                gradp[wv][s * 6 + 0] = g0;
                gradp[wv][s * 6 + 1] = g1;
                gradp[wv][s * 6 + 2] = g2;
                gradp[wv][s * 6 + 3] = g3;
                gradp[wv][s * 6 + 4] = g4;
                gradp[wv][s * 6 + 5] = g5;
            }
        }
        __syncthreads();
        // ---------------- SGD update (deterministic fixed-order sum) ----------------
        if (tid < 96) {
            float g = gradp[0][tid];
            g += gradp[1][tid];
            g += gradp[2][tid];
            g += gradp[3][tid];
            g += gradp[4][tid];
            g += gradp[5][tid];
            g += gradp[6][tid];
            g += gradp[7][tid];
            sos[upd_idx] -= 0.1f * g;
        }
        __syncthreads();
    }

    if (tid < 96) out[tid] = sos[upd_idx];
}

extern "C" void kernel_launch(void* const* d_in, const int* in_sizes, int n_in,
                              void* d_out, int out_size, void* d_ws, size_t ws_size,
                              hipStream_t stream) {
    const float* sos_in = (const float*)d_in[0];
    const float* target = (const float*)d_in[1];
    float* outp = (float*)d_out;
    hipLaunchKernelGGL(sgd_filter, dim3(1), dim3(TPB), 0, stream, sos_in, target, outp);
}

// Round 2
// 4411.003 us; speedup vs baseline: 1.3245x; 1.3245x over previous
//
#include <hip/hip_runtime.h>
#include <math.h>

#define TPB 256   // 4 waves = 1 wave/SIMD; each thread owns 2 frequencies

// rcp + 1 Newton-Raphson step: ~0.5 ulp, 3 inst vs ~10 for IEEE div
__device__ __forceinline__ float rcp_nr(float x) {
    float r = __builtin_amdgcn_rcpf(x);
    return r * fmaf(-x, r, 2.0f);
}

// Six independent 16-lane-row partial reductions, fused DPP adds (1 inst/step).
// Chains are interleaved round-robin: each register's consecutive DPP ops are
// 6 instructions apart, covering the VALU-write -> DPP-read hazard (needs 2
// wait states); s_nop 1 covers the block-entry boundary where the compiler
// may have just produced an operand. After this, lanes with (lane&15)==15
// hold the sum of their 16-lane row for each of the 6 values.
__device__ __forceinline__ void red6_row16(float& g0, float& g1, float& g2,
                                           float& g3, float& g4, float& g5) {
    asm("s_nop 1\n\t"
        "v_add_f32 %0, %0, %0 row_shr:1 row_mask:0xf bank_mask:0xf bound_ctrl:0\n\t"
        "v_add_f32 %1, %1, %1 row_shr:1 row_mask:0xf bank_mask:0xf bound_ctrl:0\n\t"
        "v_add_f32 %2, %2, %2 row_shr:1 row_mask:0xf bank_mask:0xf bound_ctrl:0\n\t"
        "v_add_f32 %3, %3, %3 row_shr:1 row_mask:0xf bank_mask:0xf bound_ctrl:0\n\t"
        "v_add_f32 %4, %4, %4 row_shr:1 row_mask:0xf bank_mask:0xf bound_ctrl:0\n\t"
        "v_add_f32 %5, %5, %5 row_shr:1 row_mask:0xf bank_mask:0xf bound_ctrl:0\n\t"
        "v_add_f32 %0, %0, %0 row_shr:2 row_mask:0xf bank_mask:0xf bound_ctrl:0\n\t"
        "v_add_f32 %1, %1, %1 row_shr:2 row_mask:0xf bank_mask:0xf bound_ctrl:0\n\t"
        "v_add_f32 %2, %2, %2 row_shr:2 row_mask:0xf bank_mask:0xf bound_ctrl:0\n\t"
        "v_add_f32 %3, %3, %3 row_shr:2 row_mask:0xf bank_mask:0xf bound_ctrl:0\n\t"
        "v_add_f32 %4, %4, %4 row_shr:2 row_mask:0xf bank_mask:0xf bound_ctrl:0\n\t"
        "v_add_f32 %5, %5, %5 row_shr:2 row_mask:0xf bank_mask:0xf bound_ctrl:0\n\t"
        "v_add_f32 %0, %0, %0 row_shr:4 row_mask:0xf bank_mask:0xf bound_ctrl:0\n\t"
        "v_add_f32 %1, %1, %1 row_shr:4 row_mask:0xf bank_mask:0xf bound_ctrl:0\n\t"
        "v_add_f32 %2, %2, %2 row_shr:4 row_mask:0xf bank_mask:0xf bound_ctrl:0\n\t"
        "v_add_f32 %3, %3, %3 row_shr:4 row_mask:0xf bank_mask:0xf bound_ctrl:0\n\t"
        "v_add_f32 %4, %4, %4 row_shr:4 row_mask:0xf bank_mask:0xf bound_ctrl:0\n\t"
        "v_add_f32 %5, %5, %5 row_shr:4 row_mask:0xf bank_mask:0xf bound_ctrl:0\n\t"
        "v_add_f32 %0, %0, %0 row_shr:8 row_mask:0xf bank_mask:0xf bound_ctrl:0\n\t"
        "v_add_f32 %1, %1, %1 row_shr:8 row_mask:0xf bank_mask:0xf bound_ctrl:0\n\t"
        "v_add_f32 %2, %2, %2 row_shr:8 row_mask:0xf bank_mask:0xf bound_ctrl:0\n\t"
        "v_add_f32 %3, %3, %3 row_shr:8 row_mask:0xf bank_mask:0xf bound_ctrl:0\n\t"
        "v_add_f32 %4, %4, %4 row_shr:8 row_mask:0xf bank_mask:0xf bound_ctrl:0\n\t"
        "v_add_f32 %5, %5, %5 row_shr:8 row_mask:0xf bank_mask:0xf bound_ctrl:0"
        : "+v"(g0), "+v"(g1), "+v"(g2), "+v"(g3), "+v"(g4), "+v"(g5));
}

__global__ __launch_bounds__(TPB, 1)
void sgd_filter(const float* __restrict__ sos_in,
                const float* __restrict__ target,
                float* __restrict__ out) {
    // sections padded to 8 floats: [b0 b1 b2 a0 a1 a2 pad pad]
    __shared__ __align__(16) float sos[16 * 8];
    // 16 row-partials (4 rows/wave x 4 waves) x 16 sections x 6 coeffs (padded to 8)
    __shared__ __align__(16) float gpart[16][128];

    const int tid = threadIdx.x;
    const int upd_addr = (tid / 6) * 8 + (tid % 6); // meaningful for tid<96

    float myc = 0.0f;                 // update threads own their coefficient
    if (tid < 96) { myc = sos_in[tid]; sos[upd_addr] = myc; }

    // Two frequencies per thread: fA = tid, fB = tid + 256
    const float wA = (float)((double)tid * (3.14159265358979323846 / 511.0));
    const float wB = (float)((double)(tid + 256) * (3.14159265358979323846 / 511.0));
    const float c1A = cosf(wA), s1A = -sinf(wA);
    const float c1B = cosf(wB), s1B = -sinf(wB);
    const float c2A = c1A * c1A - s1A * s1A, s2A = 2.0f * c1A * s1A;
    const float c2B = c1B * c1B - s1B * s1B, s2B = 2.0f * c1B * s1B;
    const float tgtA = target[tid];
    const float tgtB = target[tid + 256];
    const float KC = 40.0f / (512.0f * 2.302585092994046f); // 40/(n*ln10)

    __syncthreads();

    float BrA[16], BiA[16], ArA[16], AiA[16], iAA[16];
    float BrB[16], BiB[16], ArB[16], AiB[16], iAB[16];

    for (int it = 0; it < 1000; ++it) {
        // ---------------- forward: H = prod_s B_s/A_s (both freqs) ----------------
        float HrA = 1.0f, HiA = 0.0f, HrB = 1.0f, HiB = 0.0f;
#pragma unroll
        for (int s = 0; s < 16; ++s) {
            const float4 v0 = *(const float4*)&sos[s * 8];     // b0 b1 b2 a0
            const float2 v1 = *(const float2*)&sos[s * 8 + 4]; // a1 a2
            {   // freq A
                const float Br = fmaf(v0.z, c2A, fmaf(v0.y, c1A, v0.x));
                const float Bi = fmaf(v0.z, s2A, v0.y * s1A);
                const float Ar = fmaf(v1.y, c2A, fmaf(v1.x, c1A, v0.w));
                const float Ai = fmaf(v1.y, s2A, v1.x * s1A);
                const float inv = rcp_nr(fmaf(Ar, Ar, Ai * Ai));
                const float qr = fmaf(Br, Ar, Bi * Ai) * inv;
                const float qi = fmaf(Bi, Ar, -(Br * Ai)) * inv;
                const float nHr = fmaf(HrA, qr, -(HiA * qi));
                HiA = fmaf(HrA, qi, HiA * qr);
                HrA = nHr;
                BrA[s] = Br; BiA[s] = Bi; ArA[s] = Ar; AiA[s] = Ai; iAA[s] = inv;
            }
            {   // freq B
                const float Br = fmaf(v0.z, c2B, fmaf(v0.y, c1B, v0.x));
                const float Bi = fmaf(v0.z, s2B, v0.y * s1B);
                const float Ar = fmaf(v1.y, c2B, fmaf(v1.x, c1B, v0.w));
                const float Ai = fmaf(v1.y, s2B, v1.x * s1B);
                const float inv = rcp_nr(fmaf(Ar, Ar, Ai * Ai));
                const float qr = fmaf(Br, Ar, Bi * Ai) * inv;
                const float qi = fmaf(Bi, Ar, -(Br * Ai)) * inv;
                const float nHr = fmaf(HrB, qr, -(HiB * qi));
                HiB = fmaf(HrB, qi, HiB * qr);
                HrB = nHr;
                BrB[s] = Br; BiB[s] = Bi; ArB[s] = Ar; AiB[s] = Ai; iAB[s] = inv;
            }
        }
        const float magA = sqrtf(fmaf(HrA, HrA, HiA * HiA));
        const float magB = sqrtf(fmaf(HrB, HrB, HiB * HiB));
        const float dA = 20.0f * log10f(magA + 1e-8f) - tgtA;
        const float dB_ = 20.0f * log10f(magB + 1e-8f) - tgtB;
        const float KA = KC * dA * magA * rcp_nr(magA + 1e-8f);
        const float KB = KC * dB_ * magB * rcp_nr(magB + 1e-8f);

        // ---------------- backward + per-row reduce ----------------
#pragma unroll
        for (int s = 0; s < 16; ++s) {
            // freq A comps
            const float iBA = rcp_nr(fmaf(BrA[s], BrA[s], BiA[s] * BiA[s]));
            const float UBA = KA * iBA;
            const float PbA = UBA * BrA[s], QbA = UBA * BiA[s];
            const float UAA = -(KA * iAA[s]);
            const float PaA = UAA * ArA[s], QaA = UAA * AiA[s];
            // freq B comps
            const float iBB = rcp_nr(fmaf(BrB[s], BrB[s], BiB[s] * BiB[s]));
            const float UBB = KB * iBB;
            const float PbB = UBB * BrB[s], QbB = UBB * BiB[s];
            const float UAB = -(KB * iAB[s]);
            const float PaB = UAB * ArB[s], QaB = UAB * AiB[s];
            // pairwise pre-add (halves reduction trees vs 1 freq/thread)
            float g0 = PbA + PbB;
            float g1 = fmaf(c1A, PbA, s1A * QbA) + fmaf(c1B, PbB, s1B * QbB);
            float g2 = fmaf(c2A, PbA, s2A * QbA) + fmaf(c2B, PbB, s2B * QbB);
            float g3 = PaA + PaB;
            float g4 = fmaf(c1A, PaA, s1A * QaA) + fmaf(c1B, PaB, s1B * QaB);
            float g5 = fmaf(c2A, PaA, s2A * QaA) + fmaf(c2B, PaB, s2B * QaB);

            red6_row16(g0, g1, g2, g3, g4, g5);

            if ((tid & 15) == 15) {          // 16 row-leader lanes, row r = tid>>4
                float* p = &gpart[tid >> 4][s * 8];
                p[0] = g0; p[1] = g1; p[2] = g2; p[3] = g3; p[4] = g4; p[5] = g5;
            }
        }
        __syncthreads();
        // ---------------- SGD update (deterministic fixed-order sum) ----------------
        if (tid < 96) {
            float a0 = 0.0f, a1 = 0.0f, a2 = 0.0f, a3 = 0.0f;
#pragma unroll
            for (int r = 0; r < 4; ++r) {
                a0 += gpart[4 * r + 0][upd_addr];
                a1 += gpart[4 * r + 1][upd_addr];
                a2 += gpart[4 * r + 2][upd_addr];
                a3 += gpart[4 * r + 3][upd_addr];
            }
            const float g = (a0 + a1) + (a2 + a3);
            myc = fmaf(-0.1f, g, myc);
            sos[upd_addr] = myc;
        }
        __syncthreads();
    }

    if (tid < 96) out[tid] = myc;
}

extern "C" void kernel_launch(void* const* d_in, const int* in_sizes, int n_in,
                              void* d_out, int out_size, void* d_ws, size_t ws_size,
                              hipStream_t stream) {
    const float* sos_in = (const float*)d_in[0];
    const float* target = (const float*)d_in[1];
    float* outp = (float*)d_out;
    hipLaunchKernelGGL(sgd_filter, dim3(1), dim3(TPB), 0, stream, sos_in, target, outp);
}

// Round 3
// 4301.539 us; speedup vs baseline: 1.3582x; 1.0254x over previous
//
#include <hip/hip_runtime.h>
#include <math.h>

#define TPB 512   // 8 waves = 2 waves/SIMD for latency hiding

// rcp + 1 Newton-Raphson step: ~0.5 ulp, 3 inst vs ~10 for IEEE div
__device__ __forceinline__ float rcp_nr(float x) {
    float r = __builtin_amdgcn_rcpf(x);
    return r * fmaf(-x, r, 2.0f);
}

// Six independent 4-lane-group partial reductions, fused DPP adds (1 inst/step).
// Round-robin interleave gives each register 6-inst spacing (VALU->DPP-operand
// hazard needs 2 wait states); s_nop 1 covers the block-entry boundary.
// After this, lanes with (lane&3)==3 hold the sum of their 4-lane group.
__device__ __forceinline__ void red6_g4(float& g0, float& g1, float& g2,
                                        float& g3, float& g4, float& g5) {
    asm("s_nop 1\n\t"
        "v_add_f32 %0, %0, %0 row_shr:1 row_mask:0xf bank_mask:0xf bound_ctrl:0\n\t"
        "v_add_f32 %1, %1, %1 row_shr:1 row_mask:0xf bank_mask:0xf bound_ctrl:0\n\t"
        "v_add_f32 %2, %2, %2 row_shr:1 row_mask:0xf bank_mask:0xf bound_ctrl:0\n\t"
        "v_add_f32 %3, %3, %3 row_shr:1 row_mask:0xf bank_mask:0xf bound_ctrl:0\n\t"
        "v_add_f32 %4, %4, %4 row_shr:1 row_mask:0xf bank_mask:0xf bound_ctrl:0\n\t"
        "v_add_f32 %5, %5, %5 row_shr:1 row_mask:0xf bank_mask:0xf bound_ctrl:0\n\t"
        "v_add_f32 %0, %0, %0 row_shr:2 row_mask:0xf bank_mask:0xf bound_ctrl:0\n\t"
        "v_add_f32 %1, %1, %1 row_shr:2 row_mask:0xf bank_mask:0xf bound_ctrl:0\n\t"
        "v_add_f32 %2, %2, %2 row_shr:2 row_mask:0xf bank_mask:0xf bound_ctrl:0\n\t"
        "v_add_f32 %3, %3, %3 row_shr:2 row_mask:0xf bank_mask:0xf bound_ctrl:0\n\t"
        "v_add_f32 %4, %4, %4 row_shr:2 row_mask:0xf bank_mask:0xf bound_ctrl:0\n\t"
        "v_add_f32 %5, %5, %5 row_shr:2 row_mask:0xf bank_mask:0xf bound_ctrl:0"
        : "+v"(g0), "+v"(g1), "+v"(g2), "+v"(g3), "+v"(g4), "+v"(g5));
}

// 4-lane combine for the update stage (lane (tid&3)==3 gets group total)
__device__ __forceinline__ float red1_g4(float g) {
    asm("s_nop 1\n\t"
        "v_add_f32 %0, %0, %0 row_shr:1 row_mask:0xf bank_mask:0xf bound_ctrl:0\n\t"
        "s_nop 1\n\t"
        "v_add_f32 %0, %0, %0 row_shr:2 row_mask:0xf bank_mask:0xf bound_ctrl:0"
        : "+v"(g));
    return g;
}

__global__ __launch_bounds__(TPB, 2)
void sgd_filter(const float* __restrict__ sos_in,
                const float* __restrict__ target,
                float* __restrict__ out) {
    // sections padded to 8 floats: [b0 b1 b2 a0 a1 a2 pad pad]
    __shared__ __align__(16) float sos[16 * 8];
    // 128 group-partials (4-lane groups) x (16 sections x 8), stride 132 to
    // de-alias banks (132 mod 32 = 4 -> row r adds 4r to bank index)
    __shared__ __align__(16) float gpart[128][132];

    const int tid = threadIdx.x;

    if (tid < 96) sos[(tid / 6) * 8 + (tid % 6)] = sos_in[tid];

    // Update-stage identity: 4 threads per coefficient u = tid>>2 (tid<384);
    // lane (tid&3)==3 owns the coefficient value.
    const int u = tid >> 2;
    const int chunk = tid & 3;
    const int ucol = (u / 6) * 8 + (u % 6);        // meaningful for tid<384
    const bool upd = (tid < 384);
    const bool writer = upd && ((tid & 3) == 3);
    float myc = 0.0f;
    if (writer) myc = sos_in[u];

    // Per-thread frequency constants
    const float w  = (float)((double)tid * (3.14159265358979323846 / 511.0));
    const float c1 = cosf(w);
    const float s1 = -sinf(w);           // z1 = e^{-jw}
    const float c2 = c1 * c1 - s1 * s1;  // z2 = z1^2
    const float s2 = 2.0f * c1 * s1;
    const float tgt = target[tid];
    const float KC = 40.0f / (512.0f * 2.302585092994046f); // 40/(n*ln10)

    __syncthreads();

    // Unscaled per-section gradient directions (96 VGPRs) — the only
    // cross-section coupling is the scalar K, applied in the backward pass.
    float tb0[16], tb1[16], tb2[16], ta0[16], ta1[16], ta2[16];

    for (int it = 0; it < 1000; ++it) {
        // ---- forward: log2|H| = 0.5 * sum(log2|B|^2 - log2|A|^2) ----
        float L = 0.0f;
#pragma unroll
        for (int s = 0; s < 16; ++s) {
            const float4 v0 = *(const float4*)&sos[s * 8];     // b0 b1 b2 a0
            const float2 v1 = *(const float2*)&sos[s * 8 + 4]; // a1 a2
            const float Br = fmaf(v0.z, c2, fmaf(v0.y, c1, v0.x));
            const float Bi = fmaf(v0.z, s2, v0.y * s1);
            const float Ar = fmaf(v1.y, c2, fmaf(v1.x, c1, v0.w));
            const float Ai = fmaf(v1.y, s2, v1.x * s1);
            const float nB = fmaf(Br, Br, Bi * Bi);
            const float nA = fmaf(Ar, Ar, Ai * Ai);
            L += __builtin_amdgcn_logf(nB) - __builtin_amdgcn_logf(nA);
            const float iB = rcp_nr(nB);
            const float iA = rcp_nr(nA);
            tb0[s] = Br * iB;
            tb1[s] = fmaf(c1, Br, s1 * Bi) * iB;   // Re(z1 conjB)/|B|^2
            tb2[s] = fmaf(c2, Br, s2 * Bi) * iB;   // Re(z2 conjB)/|B|^2
            ta0[s] = Ar * iA;
            ta1[s] = fmaf(c1, Ar, s1 * Ai) * iA;
            ta2[s] = fmaf(c2, Ar, s2 * Ai) * iA;
        }
        const float mag   = __builtin_amdgcn_exp2f(0.5f * L);
        const float magpe = mag + 1e-8f;
        const float indB  = 6.020599913279624f * __builtin_amdgcn_logf(magpe); // 20*log10
        const float diff  = indB - tgt;
        const float K  = KC * diff * mag * rcp_nr(magpe);
        const float Kn = -K;

        // ---- backward: scale by K, 2-step DPP group-reduce, store partials ----
#pragma unroll
        for (int s = 0; s < 16; ++s) {
            float g0 = K * tb0[s];
            float g1 = K * tb1[s];
            float g2 = K * tb2[s];
            float g3 = Kn * ta0[s];
            float g4 = Kn * ta1[s];
            float g5 = Kn * ta2[s];
            red6_g4(g0, g1, g2, g3, g4, g5);
            if (writer || (tid >= 384 && (tid & 3) == 3)) { // (tid&3)==3, all waves
                float* p = &gpart[tid >> 2][s * 8];
                *(float4*)p       = make_float4(g0, g1, g2, g3);
                *(float2*)(p + 4) = make_float2(g4, g5);
            }
        }
        __syncthreads();

        // ---- update: 4 threads/coeff, 32 partials each, DPP combine ----
        if (upd) {
            float a = 0.0f, b = 0.0f;
#pragma unroll
            for (int j = 0; j < 16; ++j) {
                a += gpart[8 * j + chunk][ucol];        // rows 8j+c
                b += gpart[8 * j + 4 + chunk][ucol];    // rows 8j+4+c
            }
            float g = red1_g4(a + b);
            if (writer) {
                myc = fmaf(-0.1f, g, myc);
                sos[ucol] = myc;
            }
        }
        __syncthreads();
    }

    if (writer) out[u] = myc;
}

extern "C" void kernel_launch(void* const* d_in, const int* in_sizes, int n_in,
                              void* d_out, int out_size, void* d_ws, size_t ws_size,
                              hipStream_t stream) {
    const float* sos_in = (const float*)d_in[0];
    const float* target = (const float*)d_in[1];
    float* outp = (float*)d_out;
    hipLaunchKernelGGL(sgd_filter, dim3(1), dim3(TPB), 0, stream, sos_in, target, outp);
}